// Round 5
// baseline (678.118 us; speedup 1.0000x reference)
//
#include <hip/hip_runtime.h>
#include <hip/hip_bf16.h>

typedef unsigned short u16;
typedef __bf16 bf16x8 __attribute__((ext_vector_type(8)));
typedef float f32x4 __attribute__((ext_vector_type(4)));

#define T_TOK 1024
#define HID   2048
#define IMM   768
#define NE    8
#define TWOI  1536

static __device__ __forceinline__ u16 f2bf(float f) {
  unsigned u = __float_as_uint(f);
  u += 0x7FFFu + ((u >> 16) & 1u);   // RNE
  return (u16)(u >> 16);
}
static __device__ __forceinline__ float bf2f(u16 s) {
  return __uint_as_float(((unsigned)s) << 16);
}

// ---------------- router: logits -> softmax -> top2 -> renorm -> slot lists
__global__ __launch_bounds__(64) void router_kernel(
    const float* __restrict__ hid, const float* __restrict__ gw,
    int* __restrict__ cnt, int* __restrict__ tok_of, float* __restrict__ wslot)
{
  const int t = blockIdx.x;
  const int lane = threadIdx.x;
  float acc[NE];
#pragma unroll
  for (int e = 0; e < NE; ++e) acc[e] = 0.f;
  const float4* h4 = (const float4*)(hid + (long)t * HID);
#pragma unroll 2
  for (int c = lane; c < HID / 4; c += 64) {
    float4 x = h4[c];
#pragma unroll
    for (int e = 0; e < NE; ++e) {
      float4 w = ((const float4*)(gw + e * HID))[c];
      acc[e] += x.x * w.x + x.y * w.y + x.z * w.z + x.w * w.w;
    }
  }
#pragma unroll
  for (int e = 0; e < NE; ++e) {
    float v = acc[e];
#pragma unroll
    for (int off = 32; off > 0; off >>= 1) v += __shfl_xor(v, off, 64);
    acc[e] = v;
  }
  if (lane == 0) {
    float mx = acc[0];
#pragma unroll
    for (int e = 1; e < NE; ++e) mx = fmaxf(mx, acc[e]);
    float p[NE]; float s = 0.f;
#pragma unroll
    for (int e = 0; e < NE; ++e) { p[e] = expf(acc[e] - mx); s += p[e]; }
    const float inv = 1.f / s;
    float p1 = -1.f, p2 = -1.f; int i1 = 0, i2 = 0;
#pragma unroll
    for (int e = 0; e < NE; ++e) {
      float pe = p[e] * inv;
      if (pe > p1)      { p2 = p1; i2 = i1; p1 = pe; i1 = e; }
      else if (pe > p2) { p2 = pe; i2 = e; }
    }
    const float wsum = p1 + p2;
    int s1 = atomicAdd(&cnt[i1], 1);
    tok_of[i1 * T_TOK + s1] = t;
    wslot[i1 * T_TOK + s1] = p1 / wsum;
    int s2 = atomicAdd(&cnt[i2], 1);
    tok_of[i2 * T_TOK + s2] = t;
    wslot[i2 * T_TOK + s2] = p2 / wsum;
  }
}

// ---------------- hidden fp32 -> bf16
__global__ __launch_bounds__(256) void cvt_kernel(
    const float* __restrict__ in, u16* __restrict__ out)
{
  const int i = blockIdx.x * 256 + threadIdx.x;   // grid sized exactly: T*H/4 threads
  float4 x = ((const float4*)in)[i];
  ushort4 o;
  o.x = f2bf(x.x); o.y = f2bf(x.y); o.z = f2bf(x.z); o.w = f2bf(x.w);
  ((ushort4*)out)[i] = o;
}

// ---------------- grouped B^T GEMM over expert slot-space.
// Tile 256x64 (BM=256 -> each B weight panel streamed from HBM exactly once),
// BK=32, 4 waves (each 64x64 out). K split KS ways for block-count; GEMM1
// writes bf16 partials (silu reduces), GEMM2 atomicAdds all chunks into out.
// 1D grid with bijective chunked XCD swizzle: per-expert id span == total/8,
// so each expert maps to one XCD (A panel L2-resident, weights cross L2 once).
// id(orig) = m + MCAP*(n + NTILES*(ks + KS*e)), MCAP=4 capacity m-tiles.
template<int K, int KS, int NTILES, bool GATHER_A, bool OUT_ATOMIC>
__global__ __launch_bounds__(256, 3) void gemm_moe(
    const u16* __restrict__ A, int lda, long a_zoff,
    const float* __restrict__ B, long b_zoff,
    const int* __restrict__ tok_of, const int* __restrict__ cnt,
    u16* __restrict__ Cb, long ks_coff, float* __restrict__ Cf,
    int ldc, long c_zoff)
{
  constexpr int BM = 256, BN = 64, BK = 32;
  constexpr int MCAP = 4;                 // capacity m-tiles (cnt can reach 1024)
  constexpr int LSTR = BK + 8;            // pad: 80B rows -> 2-way (free) frag reads
  constexpr int KH  = K / KS;
  constexpr int NKT = KH / BK;
  constexpr int TOTAL = MCAP * NTILES * NE * KS;
  static_assert(NKT >= 2 && (KH % BK) == 0, "bad K chunk");
  static_assert((TOTAL % 8) == 0, "swizzle needs total%8==0");

  // bijective chunked XCD swizzle
  const int phys = blockIdx.x;
  const int orig = (phys & 7) * (TOTAL / 8) + (phys >> 3);
  const int mi   = orig & (MCAP - 1);
  const int r1   = orig >> 2;
  const int n_t  = r1 % NTILES;
  const int z    = r1 / NTILES;
  const int ks   = z % KS;
  const int e    = z / KS;
  const int kb   = ks * KH;

  const int nrow = cnt[e];
  const long m0 = (long)mi * BM;
  if (m0 >= nrow) return;                 // uniform per block

  __shared__ __align__(16) u16 As[2][BM * LSTR];   // 40 KiB
  __shared__ __align__(16) u16 Bs[2][BN * LSTR];   // 10 KiB

  const int tid  = threadIdx.x;
  const int lane = tid & 63;
  const int wm   = tid >> 6;              // wave = m-quadrant (4 x 64 rows)
  const int lrow = lane & 15;
  const int lk   = (lane >> 4) << 3;      // 8 contiguous k per lane

  const long n0 = (long)n_t * BN;

  // staging: thread t owns A row m0+t (64B/step) and B col (t>>2), kc=(t&3)
  const u16* ap;
  if constexpr (GATHER_A) {
    ap = A + (long)tok_of[e * T_TOK + m0 + tid] * lda + kb;
  } else {
    ap = A + a_zoff * e + (m0 + tid) * (long)lda + kb;
  }
  const float* bp = B + b_zoff * e + (n0 + (tid >> 2)) * (long)K + kb + (tid & 3) * 8;

  uint4 sa0, sa1, sa2, sa3; float4 sb0, sb1;

  auto gload = [&](int kk) {
    const uint4* a4 = (const uint4*)(ap + kk);
    sa0 = a4[0]; sa1 = a4[1]; sa2 = a4[2]; sa3 = a4[3];
    sb0 = *(const float4*)(bp + kk);
    sb1 = *(const float4*)(bp + kk + 4);
  };
  auto swrite = [&](int buf) {
    uint4* aw = (uint4*)&As[buf][tid * LSTR];
    aw[0] = sa0; aw[1] = sa1; aw[2] = sa2; aw[3] = sa3;
    *(uint4*)&Bs[buf][(tid >> 2) * LSTR + (tid & 3) * 8] = make_uint4(
      (unsigned)f2bf(sb0.x) | ((unsigned)f2bf(sb0.y) << 16),
      (unsigned)f2bf(sb0.z) | ((unsigned)f2bf(sb0.w) << 16),
      (unsigned)f2bf(sb1.x) | ((unsigned)f2bf(sb1.y) << 16),
      (unsigned)f2bf(sb1.z) | ((unsigned)f2bf(sb1.w) << 16));
  };

  f32x4 acc[4][4];
  const f32x4 zero4 = {0.f, 0.f, 0.f, 0.f};
#pragma unroll
  for (int m = 0; m < 4; ++m)
#pragma unroll
    for (int n = 0; n < 4; ++n) acc[m][n] = zero4;

  auto compute = [&](int buf) {
    bf16x8 af[4], bfv[4];
#pragma unroll
    for (int m = 0; m < 4; ++m)
      af[m] = *(const bf16x8*)&As[buf][(wm * 64 + m * 16 + lrow) * LSTR + lk];
#pragma unroll
    for (int n = 0; n < 4; ++n)
      bfv[n] = *(const bf16x8*)&Bs[buf][(n * 16 + lrow) * LSTR + lk];
#pragma unroll
    for (int m = 0; m < 4; ++m)
#pragma unroll
      for (int n = 0; n < 4; ++n)
        acc[m][n] = __builtin_amdgcn_mfma_f32_16x16x32_bf16(af[m], bfv[n], acc[m][n], 0, 0, 0);
  };

  gload(0);
  swrite(0);
  __syncthreads();
  int cur = 0;
#pragma unroll 1
  for (int kt = 0; kt < NKT - 1; ++kt) {
    gload((kt + 1) * BK);    // issue next tile's global loads (hide under MFMA)
    compute(cur);
    swrite(cur ^ 1);
    __syncthreads();
    cur ^= 1;
  }
  compute(cur);

  // epilogue: per 16x16 frag, col = lane&15, row = (lane>>4)*4 + j  [m89]
  const int rloc = wm * 64 + ((lane >> 4) << 2);
  const long cbase = n0 + lrow;
  u16* CbE = Cb + (long)ks * ks_coff + c_zoff * e;
#pragma unroll
  for (int m = 0; m < 4; ++m) {
#pragma unroll
    for (int n = 0; n < 4; ++n) {
#pragma unroll
      for (int j = 0; j < 4; ++j) {
        const long slot = m0 + rloc + m * 16 + j;
        const long col = cbase + n * 16;
        if constexpr (OUT_ATOMIC) {
          if (slot < nrow) {
            const long tok = tok_of[e * T_TOK + slot];
            atomicAdd(Cf + tok * ldc + col, acc[m][n][j]);
          }
        } else {
          CbE[slot * ldc + col] = f2bf(acc[m][n][j]);
        }
      }
    }
  }
}

// ---------------- slot-space: hp[g,i] = wslot[g] * silu(sum_p g_p) * (sum_p u_p)
template<int KS>
__global__ __launch_bounds__(256) void silu_kernel(
    const u16* __restrict__ gu, long part_stride, const float* __restrict__ wslot,
    u16* __restrict__ hp)
{
  const int c = blockIdx.x * 256 + threadIdx.x;   // grid: E*T*IMM/8 threads
  const int idx = c << 3;
  const int g = idx / IMM;            // global slot 0..E*T-1
  const int i0 = idx - g * IMM;
  float gacc[8], uacc[8];
#pragma unroll
  for (int q = 0; q < 8; ++q) { gacc[q] = 0.f; uacc[q] = 0.f; }
#pragma unroll
  for (int p = 0; p < KS; ++p) {
    const u16* gp = gu + (long)p * part_stride + (long)g * TWOI + i0;
    uint4 gv = *(const uint4*)gp;
    uint4 uv = *(const uint4*)(gp + IMM);
    const unsigned* gw_ = (const unsigned*)&gv;
    const unsigned* uw_ = (const unsigned*)&uv;
#pragma unroll
    for (int q = 0; q < 4; ++q) {
      gacc[2 * q]     += bf2f((u16)(gw_[q] & 0xFFFFu));
      gacc[2 * q + 1] += bf2f((u16)(gw_[q] >> 16));
      uacc[2 * q]     += bf2f((u16)(uw_[q] & 0xFFFFu));
      uacc[2 * q + 1] += bf2f((u16)(uw_[q] >> 16));
    }
  }
  const float cw = wslot[g];
  unsigned outw[4];
#pragma unroll
  for (int q = 0; q < 4; ++q) {
    float h0 = cw * uacc[2 * q]     * (gacc[2 * q]     / (1.f + __expf(-gacc[2 * q])));
    float h1 = cw * uacc[2 * q + 1] * (gacc[2 * q + 1] / (1.f + __expf(-gacc[2 * q + 1])));
    outw[q] = (unsigned)f2bf(h0) | ((unsigned)f2bf(h1) << 16);
  }
  *(uint4*)(hp + (long)g * IMM + i0) = make_uint4(outw[0], outw[1], outw[2], outw[3]);
}

extern "C" void kernel_launch(void* const* d_in, const int* in_sizes, int n_in,
                              void* d_out, int out_size, void* d_ws, size_t ws_size,
                              hipStream_t stream) {
  const float* hid = (const float*)d_in[0];   // [T, H]
  const float* gw  = (const float*)d_in[1];   // [E, H]
  const float* wgu = (const float*)d_in[2];   // [E, 2I, H]
  const float* wd  = (const float*)d_in[3];   // [E, H, I]
  float* out = (float*)d_out;                 // [T, H] fp32

  const long GU_PART = (long)NE * T_TOK * TWOI;    // elements per gu partial (24 MiB)
  char* ws = (char*)d_ws;
  u16*   hidb   = (u16*)ws;                                   // 4 MiB [T][H] bf16
  int*   cnt    = (int*)(ws + (4l << 20));                    // 4 KiB pad
  int*   tok_of = (int*)(ws + (4l << 20) + (1l << 12));       // 32 KiB [E][T]
  float* wslot  = (float*)(ws + (4l << 20) + (1l << 12) + (1l << 15));
  u16*   gu     = (u16*)(ws + (4l << 20) + (1l << 17));       // KS x 24 MiB partials
  // hp placed after gu (position depends on KS, computed below)

  hipMemsetAsync(d_out, 0, (size_t)out_size * sizeof(float), stream);
  hipMemsetAsync(ws + (4l << 20), 0, (1l << 17), stream);

  router_kernel<<<T_TOK, 64, 0, stream>>>(hid, gw, cnt, tok_of, wslot);
  cvt_kernel<<<(T_TOK * HID / 4) / 256, 256, 0, stream>>>(hid, hidb);

  const size_t base = (4l << 20) + (1l << 17);
  const size_t need4 = base + 4 * GU_PART * 2 + (long)NE * T_TOK * IMM * 2;
  const bool ks4 = ws_size >= need4;   // constant across calls -> capture-safe

  if (ks4) {
    u16* hp = (u16*)(ws + base + 4 * GU_PART * 2);
    gemm_moe<HID, 4, TWOI / 64, true, false>
        <<<4 * (TWOI / 64) * NE * 4, 256, 0, stream>>>(
        hidb, HID, 0, wgu, (long)TWOI * HID,
        tok_of, cnt, gu, GU_PART, nullptr, TWOI, (long)T_TOK * TWOI);
    silu_kernel<4><<<(NE * T_TOK * IMM / 8) / 256, 256, 0, stream>>>(
        gu, GU_PART, wslot, hp);
    gemm_moe<IMM, 4, HID / 64, false, true>
        <<<4 * (HID / 64) * NE * 4, 256, 0, stream>>>(
        hp, IMM, (long)T_TOK * IMM, wd, (long)HID * IMM,
        tok_of, cnt, nullptr, 0, out, HID, 0);
  } else {
    u16* hp = (u16*)(ws + base + 2 * GU_PART * 2);
    gemm_moe<HID, 2, TWOI / 64, true, false>
        <<<4 * (TWOI / 64) * NE * 2, 256, 0, stream>>>(
        hidb, HID, 0, wgu, (long)TWOI * HID,
        tok_of, cnt, gu, GU_PART, nullptr, TWOI, (long)T_TOK * TWOI);
    silu_kernel<2><<<(NE * T_TOK * IMM / 8) / 256, 256, 0, stream>>>(
        gu, GU_PART, wslot, hp);
    gemm_moe<IMM, 2, HID / 64, false, true>
        <<<4 * (HID / 64) * NE * 2, 256, 0, stream>>>(
        hp, IMM, (long)T_TOK * IMM, wd, (long)HID * IMM,
        tok_of, cnt, nullptr, 0, out, HID, 0);
  }
}